// Round 4
// baseline (1276.950 us; speedup 1.0000x reference)
//
#include <hip/hip_runtime.h>
#include <hip/hip_bf16.h>

typedef __bf16 bf16_t;
typedef __bf16 bf16x4 __attribute__((ext_vector_type(4)));
typedef __bf16 bf16x8 __attribute__((ext_vector_type(8)));
typedef float f32x4 __attribute__((ext_vector_type(4)));
typedef float f32x16 __attribute__((ext_vector_type(16)));

#define B_ 2
#define S_ 2048
#define HID_ 5120
#define H_ 32
#define D_NOPE_ 128
#define D_ROPE_ 64
#define D_V_ 128
#define D_Q_ 192
#define EPS_ 1e-6f

// async global->LDS, 16B per lane, linear LDS dest (wave-uniform base + lane*16)
#define GLDS16(g, l)                                                          \
  __builtin_amdgcn_global_load_lds(                                           \
      (const __attribute__((address_space(1))) void*)(g),                     \
      (__attribute__((address_space(3))) void*)(l), 16, 0, 0)

// ---------------------------------------------------------------------------
// fp32 -> bf16 cast, 8 elems/thread. n must be divisible by 2048 (all are).
// ---------------------------------------------------------------------------
__global__ __launch_bounds__(256) void f32_to_bf16_k(const float* __restrict__ x,
                                                     bf16_t* __restrict__ y, long n) {
  long i = ((long)blockIdx.x * 256 + threadIdx.x) * 8;
  if (i + 8 <= n) {
    float4 f0 = *(const float4*)(x + i);
    float4 f1 = *(const float4*)(x + i + 4);
    bf16x8 o;
    o[0] = (bf16_t)f0.x; o[1] = (bf16_t)f0.y; o[2] = (bf16_t)f0.z; o[3] = (bf16_t)f0.w;
    o[4] = (bf16_t)f1.x; o[5] = (bf16_t)f1.y; o[6] = (bf16_t)f1.z; o[7] = (bf16_t)f1.w;
    *(bf16x8*)(y + i) = o;
  }
}

// ---------------------------------------------------------------------------
// gemm128: C[M,N] = A[M,K] @ W[N,K]^T, bf16 in, fp32 MFMA accumulate.
// m97 structure: 128x128 tile, BK=32, 256 thr (4 waves 2x2), global_load_lds.
// CMODE: 0 = bf16 C; 1 = fp32 C; 2 = split-kv epilogue writing FRAGMENT-MAJOR
// K/V caches for flash_attn4 (see flash kernel header for the layouts):
//   n -> (h = n/256, c = n%256); c<128 -> KnF tiles; c>=128 -> VFg tiles.
// A-frag: A[m=lane&15][k=(lane>>4)*8+j]; B-frag: W[n=lane&15][k=...];
// D: col=lane&15 (=n), row=(lane>>4)*4+reg (=m)   (HW-verified layouts)
// ---------------------------------------------------------------------------
template <int CMODE>
__global__ __launch_bounds__(256) void gemm128(const bf16_t* __restrict__ A,
                                               const bf16_t* __restrict__ W,
                                               void* __restrict__ Cv,
                                               bf16_t* __restrict__ vTp,
                                               int M, int N, int K) {
  __shared__ bf16_t As[128 * 32];
  __shared__ bf16_t Ws[128 * 32];
  const int tid = threadIdx.x;
  const int lane = tid & 63;
  const int wave = tid >> 6;
  const int bm = blockIdx.y * 128;
  const int bn = blockIdx.x * 128;
  const int wm = (wave >> 1) * 64;
  const int wn = (wave & 1) * 64;
  const int ll = lane & 15;
  const int kg = (lane >> 4) * 8;
  const int r0 = tid >> 2;
  const int cc0 = (tid & 3) * 8;
  const bf16_t* Ag0 = A + (size_t)(bm + r0) * K + cc0;
  const bf16_t* Ag1 = A + (size_t)(bm + 64 + r0) * K + cc0;
  const bf16_t* Wg0 = W + (size_t)(bn + r0) * K + cc0;
  const bf16_t* Wg1 = W + (size_t)(bn + 64 + r0) * K + cc0;
  bf16_t* Al0 = &As[tid * 8];
  bf16_t* Al1 = &As[(tid + 256) * 8];
  bf16_t* Wl0 = &Ws[tid * 8];
  bf16_t* Wl1 = &Ws[(tid + 256) * 8];

  f32x4 acc[4][4];
#pragma unroll
  for (int m = 0; m < 4; m++)
#pragma unroll
    for (int n = 0; n < 4; n++) acc[m][n] = {};

  for (int k0 = 0; k0 < K; k0 += 32) {
    GLDS16(Ag0 + k0, Al0);
    GLDS16(Ag1 + k0, Al1);
    GLDS16(Wg0 + k0, Wl0);
    GLDS16(Wg1 + k0, Wl1);
    __syncthreads();  // drains vmcnt -> LDS tile ready
    bf16x8 af[4], bfr[4];
#pragma unroll
    for (int m = 0; m < 4; m++)
      af[m] = *(const bf16x8*)&As[(wm + m * 16 + ll) * 32 + kg];
#pragma unroll
    for (int n = 0; n < 4; n++)
      bfr[n] = *(const bf16x8*)&Ws[(wn + n * 16 + ll) * 32 + kg];
#pragma unroll
    for (int m = 0; m < 4; m++)
#pragma unroll
      for (int n = 0; n < 4; n++)
        acc[m][n] = __builtin_amdgcn_mfma_f32_16x16x32_bf16(af[m], bfr[n], acc[m][n], 0, 0, 0);
    __syncthreads();  // all reads done before next tile's DMA lands
  }

  const int rb = (lane >> 4) * 4;
  if constexpr (CMODE == 2) {
    bf16_t* KN = (bf16_t*)Cv;
#pragma unroll
    for (int m = 0; m < 4; m++)
#pragma unroll
      for (int n = 0; n < 4; n++) {
        int mrow = bm + wm + m * 16 + rb;
        int nn = bn + wn + n * 16 + ll;
        int hh2 = nn >> 8, cc = nn & 255;
        int bb = mrow >> 11, s = mrow & 2047;
        size_t tile = (size_t)(bb * H_ + hh2) * 32 + (s >> 6);
        if (cc < 128) {
          // KnF[tile][((t*8+kc)*64 + 32*hb + ml)*8 + j]
          int t = (s >> 5) & 1, ml = s & 31, kc = cc >> 4, hb = (cc >> 3) & 1, j = cc & 7;
          bf16_t* p = KN + tile * 8192 + (size_t)(((t * 8 + kc) * 64 + 32 * hb + ml) * 8 + j);
#pragma unroll
          for (int rr = 0; rr < 4; rr++) p[rr * 8] = (bf16_t)acc[m][n][rr];
        } else {
          // VFg[tile][((dn*4+kc2)*64 + 32*hb + dl)*8 + jb]  (4 consecutive j)
          int d = cc - 128;
          int kc2 = (s >> 4) & 3, hb = (s >> 3) & 1, jb = s & 7;
          int dn = d >> 5, dl = d & 31;
          bf16x4 o;
          o[0] = (bf16_t)acc[m][n][0]; o[1] = (bf16_t)acc[m][n][1];
          o[2] = (bf16_t)acc[m][n][2]; o[3] = (bf16_t)acc[m][n][3];
          *(bf16x4*)(vTp + tile * 8192 +
                     (size_t)(((dn * 4 + kc2) * 64 + 32 * hb + dl) * 8 + jb)) = o;
        }
      }
  } else {
#pragma unroll
    for (int m = 0; m < 4; m++)
#pragma unroll
      for (int n = 0; n < 4; n++) {
        int row = bm + wm + m * 16 + rb;
        int col = bn + wn + n * 16 + ll;
        if (CMODE == 1) {
          float* C = (float*)Cv;
#pragma unroll
          for (int rr = 0; rr < 4; rr++)
            C[(size_t)(row + rr) * N + col] = acc[m][n][rr];
        } else {
          bf16_t* C = (bf16_t*)Cv;
#pragma unroll
          for (int rr = 0; rr < 4; rr++)
            C[(size_t)(row + rr) * N + col] = (bf16_t)acc[m][n][rr];
        }
      }
  }
}

// ---------------------------------------------------------------------------
// Legacy 64x64 GEMM (used only for kv_a: N=576 not divisible by 128).
// ---------------------------------------------------------------------------
__global__ __launch_bounds__(256) void gemm_bt64(const bf16_t* __restrict__ A,
                                                 const bf16_t* __restrict__ W,
                                                 bf16_t* __restrict__ C,
                                                 int M, int N, int K) {
  __shared__ bf16_t As[64 * 40];
  __shared__ bf16_t Ws[64 * 40];
  const int tid = threadIdx.x;
  const int bm = blockIdx.y * 64;
  const int bn = blockIdx.x * 64;
  const int wave = tid >> 6, lane = tid & 63;
  const int wm = (wave >> 1) * 32, wn = (wave & 1) * 32;
  const int srow = tid >> 2;
  const int scol = (tid & 3) * 8;
  const bf16_t* Ap16 = A + (size_t)(bm + srow) * K + scol;
  const bf16_t* Wp = W + (size_t)(bn + srow) * K + scol;
  f32x4 acc00 = {}, acc01 = {}, acc10 = {}, acc11 = {};
  const int r = lane & 15;
  const int kq = (lane >> 4) * 8;
  for (int k0 = 0; k0 < K; k0 += 32) {
    *(bf16x8*)&As[srow * 40 + scol] = *(const bf16x8*)(Ap16 + k0);
    *(bf16x8*)&Ws[srow * 40 + scol] = *(const bf16x8*)(Wp + k0);
    __syncthreads();
    bf16x8 a0 = *(bf16x8*)&As[(wm + r) * 40 + kq];
    bf16x8 a1 = *(bf16x8*)&As[(wm + 16 + r) * 40 + kq];
    bf16x8 b0 = *(bf16x8*)&Ws[(wn + r) * 40 + kq];
    bf16x8 b1 = *(bf16x8*)&Ws[(wn + 16 + r) * 40 + kq];
    acc00 = __builtin_amdgcn_mfma_f32_16x16x32_bf16(a0, b0, acc00, 0, 0, 0);
    acc01 = __builtin_amdgcn_mfma_f32_16x16x32_bf16(a0, b1, acc01, 0, 0, 0);
    acc10 = __builtin_amdgcn_mfma_f32_16x16x32_bf16(a1, b0, acc10, 0, 0, 0);
    acc11 = __builtin_amdgcn_mfma_f32_16x16x32_bf16(a1, b1, acc11, 0, 0, 0);
    __syncthreads();
  }
  const int col = lane & 15;
  const int rb = (lane >> 4) * 4;
#pragma unroll
  for (int rr = 0; rr < 4; rr++) {
    int m0r = bm + wm + rb + rr;
    int m1r = m0r + 16;
    C[(size_t)m0r * N + (bn + wn + col)]      = (bf16_t)acc00[rr];
    C[(size_t)m0r * N + (bn + wn + 16 + col)] = (bf16_t)acc01[rr];
    C[(size_t)m1r * N + (bn + wn + col)]      = (bf16_t)acc10[rr];
    C[(size_t)m1r * N + (bn + wn + 16 + col)] = (bf16_t)acc11[rr];
  }
}

// ---------------------------------------------------------------------------
// RMSNorm (bf16 in/out, fp32 math). w is fp32 (original input weight).
// ---------------------------------------------------------------------------
__global__ __launch_bounds__(256) void rmsnorm_k(const bf16_t* __restrict__ x,
                                                 const float* __restrict__ w,
                                                 bf16_t* __restrict__ y,
                                                 int dim, int xstride) {
  const int row = blockIdx.x;
  const bf16_t* xr = x + (size_t)row * xstride;
  bf16_t* yr = y + (size_t)row * dim;
  float ss = 0.f;
  for (int i = threadIdx.x; i < dim; i += 256) {
    float v = (float)xr[i];
    ss += v * v;
  }
  for (int off = 32; off > 0; off >>= 1) ss += __shfl_down(ss, off);
  __shared__ float red[4];
  __shared__ float s_rinv;
  if ((threadIdx.x & 63) == 0) red[threadIdx.x >> 6] = ss;
  __syncthreads();
  if (threadIdx.x == 0) {
    float tot = red[0] + red[1] + red[2] + red[3];
    s_rinv = 1.0f / sqrtf(tot / (float)dim + EPS_);
  }
  __syncthreads();
  float rinv = s_rinv;
  for (int i = threadIdx.x; i < dim; i += 256)
    yr[i] = (bf16_t)((float)xr[i] * rinv * w[i]);
}

// ---------------------------------------------------------------------------
// RoPE with deinterleave (generic, used for q in-place).
// ---------------------------------------------------------------------------
__global__ __launch_bounds__(64) void rope_k(const bf16_t* __restrict__ src,
                                             bf16_t* __restrict__ dst,
                                             const int* __restrict__ pos_ids,
                                             int heads_per_pos, int sstride,
                                             int dstride) {
  __shared__ float xs[64];
  const int rrow = blockIdx.x;
  const int j = threadIdx.x;
  const bf16_t* s = src + (size_t)rrow * sstride;
  xs[j] = (float)s[j];
  __syncthreads();
  const int pos = pos_ids[rrow / heads_per_pos];
  const int i = j & 31;
  float freq = exp2f(-(float)i * 0.4152410118609203f);  // log2(10000)/32
  float ang = (float)pos * freq;
  float c, sn;
  __sincosf(ang, &sn, &c);
  float outv;
  if (j < 32)
    outv = xs[2 * j] * c - xs[2 * j + 1] * sn;
  else
    outv = xs[2 * i + 1] * c + xs[2 * i] * sn;
  dst[(size_t)rrow * dstride + j] = (bf16_t)outv;
}

// ---------------------------------------------------------------------------
// RoPE for k_pe writing the fragment-major KpeF cache:
// KpeF[(b*32+t64)*4096 + ((t*4 + (j>>4))*64 + 32*((j>>3)&1) + (s&31))*8 + (j&7)]
// ---------------------------------------------------------------------------
__global__ __launch_bounds__(64) void rope_kpe_k(const bf16_t* __restrict__ src,
                                                 bf16_t* __restrict__ kpeF,
                                                 const int* __restrict__ pos_ids) {
  __shared__ float xs[64];
  const int rrow = blockIdx.x;  // b*S + s
  const int j = threadIdx.x;
  const bf16_t* s = src + (size_t)rrow * 576;
  xs[j] = (float)s[j];
  __syncthreads();
  const int pos = pos_ids[rrow];
  const int i = j & 31;
  float freq = exp2f(-(float)i * 0.4152410118609203f);
  float ang = (float)pos * freq;
  float c, sn;
  __sincosf(ang, &sn, &c);
  float outv = (j < 32) ? xs[2 * j] * c - xs[2 * j + 1] * sn
                        : xs[2 * i + 1] * c + xs[2 * i] * sn;
  int bb = rrow >> 11, ss = rrow & 2047;
  int t64 = ss >> 6, t = (ss >> 5) & 1, ml = ss & 31;
  kpeF[(size_t)(bb * 32 + t64) * 4096 +
       (size_t)(((t * 4 + (j >> 4)) * 64 + 32 * ((j >> 3) & 1) + ml) * 8 + (j & 7))] =
      (bf16_t)outv;
}

// ---------------------------------------------------------------------------
// MFMA causal flash attention v4: 32x32x16 MFMA, 4 waves x 32 q-rows,
// K-tile 64, global_load_lds staging from fragment-major K/V caches.
//
// QK^T swapped: St[kv][q] = mfma(A=Kfrag, B=Qfrag). C/D (HW-verified):
// col=lane&31 (=q), row=(reg&3)+8*(reg>>2)+4*(lane>>5) (=kv within 32-tile).
// Because q is lane-local in both St and PV's A-frag (A[m=lane&31][k]),
// softmax+P stay in registers; the kv half-split (own lane holds kv quads
// {0-3,8-11}+4h) is fixed by one __shfl_xor(...,32) quad exchange.
//
// LDS images (== global cache tile images; staged linearly by GLDS16):
//  KF[((t*12+kc)*64 + lane)*8 + j] = K[kv=32t+(lane&31)][col=16kc+8*(lane>>5)+j]
//     (kc 0-7 from KnF tiles, kc 8-11 from KpeF tiles)
//  VF[((dn*4+kc2)*64 + lane)*8 + j] = V[kv=16kc2+8*(lane>>5)+j][d=32dn+(lane&31)]
// ---------------------------------------------------------------------------
__global__ __launch_bounds__(256) void flash_attn4(
    const bf16_t* __restrict__ q, const bf16_t* __restrict__ knF,
    const bf16_t* __restrict__ kpeF, const bf16_t* __restrict__ vF,
    bf16_t* __restrict__ attn) {
  __shared__ bf16_t KF[12288];  // 24KB
  __shared__ bf16_t VF[8192];   // 16KB
  const int tid = threadIdx.x;
  const int w = tid >> 6;
  const int lane = tid & 63;
  const int ql = lane & 31;   // q (and d) column
  const int hh = lane >> 5;   // k-half
  const int bh = blockIdx.y;
  const int b = bh >> 5, h = bh & 31;
  const int q0 = ((int)gridDim.x - 1 - (int)blockIdx.x) * 128;  // heavy first
  const int bS = b * S_;

  // Q fragments (B-operand): qf[kc] = Q[q0+32w+ql][16kc+8hh+..7] * scale*log2e
  const float qsc = 0.07216878364870322f * 1.4426950408889634f;
  bf16x8 qf[12];
  {
    const bf16_t* qp = q + (((size_t)(bS + q0 + 32 * w + ql)) * H_ + h) * D_Q_ + 8 * hh;
#pragma unroll
    for (int kc = 0; kc < 12; kc++) {
      bf16x8 raw = *(const bf16x8*)(qp + 16 * kc);
      bf16x8 sc;
#pragma unroll
      for (int j = 0; j < 8; j++) sc[j] = (bf16_t)((float)raw[j] * qsc);
      qf[kc] = sc;
    }
  }

  f32x16 acc0 = {}, acc1 = {}, acc2 = {}, acc3 = {};
  float m_run = -1e30f, l_run = 0.f;

  // staging bases (per-tile strides: KnF 8192, KpeF 4096, VFg 8192 elems)
  const bf16_t* kn_src = knF + (size_t)(b * H_ + h) * 262144 + (w * 512 + lane * 8);
  const bf16_t* kp_src = kpeF + (size_t)b * 131072 + (w * 512 + lane * 8);
  const bf16_t* v_src  = vF + (size_t)(b * H_ + h) * 262144 + tid * 8;

  const int nkt = (q0 >> 6) + 2;
  const int qg = q0 + 32 * w + ql;

  for (int kt = 0; kt < nkt; kt++) {
    const int k0 = kt * 64;
    // ---- stage tile (all linear & coalesced) ----
    GLDS16(kn_src,        &KF[(tid       ) * 8]);  // t0 kc=w
    GLDS16(kn_src + 2048, &KF[(tid +  256) * 8]);  // t0 kc=w+4
    GLDS16(kp_src,        &KF[(tid +  512) * 8]);  // t0 kc=w+8
    GLDS16(kn_src + 4096, &KF[(tid +  768) * 8]);  // t1 kc=w
    GLDS16(kn_src + 6144, &KF[(tid + 1024) * 8]);  // t1 kc=w+4
    GLDS16(kp_src + 2048, &KF[(tid + 1280) * 8]);  // t1 kc=w+8
    GLDS16(v_src,         &VF[(tid       ) * 8]);
    GLDS16(v_src + 2048,  &VF[(tid +  256) * 8]);
    GLDS16(v_src + 4096,  &VF[(tid +  512) * 8]);
    GLDS16(v_src + 6144,  &VF[(tid +  768) * 8]);
    kn_src += 8192; kp_src += 4096; v_src += 8192;
    __syncthreads();  // drain DMA -> tile ready

    // ---- QK^T: St[kv][q] ----
    f32x16 sv0 = {}, sv1 = {};
    __builtin_amdgcn_s_setprio(1);
#pragma unroll
    for (int kc = 0; kc < 12; kc++) {
      bf16x8 ak0 = *(bf16x8*)&KF[(kc * 64 + lane) * 8];
      bf16x8 ak1 = *(bf16x8*)&KF[((12 + kc) * 64 + lane) * 8];
      sv0 = __builtin_amdgcn_mfma_f32_32x32x16_bf16(ak0, qf[kc], sv0, 0, 0, 0);
      sv1 = __builtin_amdgcn_mfma_f32_32x32x16_bf16(ak1, qf[kc], sv1, 0, 0, 0);
    }
    __builtin_amdgcn_s_setprio(0);

    // ---- mask + online softmax (exp2 domain, defer-max) ----
    float tmax = -1e30f;
    if (k0 + 63 > q0 + 32 * w) {  // wave-uniform: tile touches diagonal
#pragma unroll
      for (int r = 0; r < 16; r++) {
        int kvr = (r & 3) + 8 * (r >> 2) + 4 * hh;
        float s0 = sv0[r]; if (k0 + kvr > qg) s0 = -1e30f;
        sv0[r] = s0; tmax = fmaxf(tmax, s0);
        float s1 = sv1[r]; if (k0 + 32 + kvr > qg) s1 = -1e30f;
        sv1[r] = s1; tmax = fmaxf(tmax, s1);
      }
    } else {
#pragma unroll
      for (int r = 0; r < 16; r++) {
        tmax = fmaxf(tmax, sv0[r]);
        tmax = fmaxf(tmax, sv1[r]);
      }
    }
    tmax = fmaxf(tmax, __shfl_xor(tmax, 32));
    bool need = tmax > m_run + 10.0f;  // defer-max: P bounded by 2^10
    float mnew = need ? fmaxf(m_run, tmax) : m_run;
    float al = exp2f(m_run - mnew);  // ==1 when deferred
    float rs = 0.f;
#pragma unroll
    for (int r = 0; r < 16; r++) {
      float p0 = exp2f(sv0[r] - mnew); sv0[r] = p0; rs += p0;
      float p1 = exp2f(sv1[r] - mnew); sv1[r] = p1; rs += p1;
    }
    rs += __shfl_xor(rs, 32);
    if (__any(need)) {  // rare: distribute alpha to q-rows and rescale O
#pragma unroll
      for (int r = 0; r < 16; r++) {
        float ar = __shfl(al, (r & 3) + 8 * (r >> 2) + 4 * hh);
        acc0[r] *= ar; acc1[r] *= ar; acc2[r] *= ar; acc3[r] *= ar;
      }
    }
    l_run = l_run * al + rs;
    m_run = mnew;

    // ---- P -> PV A-frags (in-register; one half-swap per quad-pair) ----
    // own lane holds kv quads rq={2qd+h...}: keep rq=2qd+hh, swap rq=2qd+1-hh
    bf16x8 pa[4];
#pragma unroll
    for (int t = 0; t < 2; t++) {
#pragma unroll
      for (int qd = 0; qd < 2; qd++) {
        bf16x4 qe, qo;
#pragma unroll
        for (int e = 0; e < 4; e++) {
          float pe = (t == 0) ? sv0[8 * qd + e]     : sv1[8 * qd + e];
          float po = (t == 0) ? sv0[8 * qd + 4 + e] : sv1[8 * qd + 4 + e];
          qe[e] = (bf16_t)pe;
          qo[e] = (bf16_t)po;
        }
        bf16x4 kept = hh ? qo : qe;
        bf16x4 sent = hh ? qe : qo;
        unsigned long long su = *(unsigned long long*)&sent;
        unsigned long long ru = __shfl_xor(su, 32);
        bf16x4 recv = *(bf16x4*)&ru;
        bf16x8 f;
#pragma unroll
        for (int e = 0; e < 4; e++) {
          f[e]     = hh ? recv[e] : kept[e];
          f[4 + e] = hh ? kept[e] : recv[e];
        }
        pa[2 * t + qd] = f;
      }
    }

    // ---- PV: O[q][d] += P @ V ----
    __builtin_amdgcn_s_setprio(1);
#pragma unroll
    for (int kc2 = 0; kc2 < 4; kc2++) {
      bf16x8 bv0 = *(bf16x8*)&VF[((0 * 4 + kc2) * 64 + lane) * 8];
      bf16x8 bv1 = *(bf16x8*)&VF[((1 * 4 + kc2) * 64 + lane) * 8];
      bf16x8 bv2 = *(bf16x8*)&VF[((2 * 4 + kc2) * 64 + lane) * 8];
      bf16x8 bv3 = *(bf16x8*)&VF[((3 * 4 + kc2) * 64 + lane) * 8];
      acc0 = __builtin_amdgcn_mfma_f32_32x32x16_bf16(pa[kc2], bv0, acc0, 0, 0, 0);
      acc1 = __builtin_amdgcn_mfma_f32_32x32x16_bf16(pa[kc2], bv1, acc1, 0, 0, 0);
      acc2 = __builtin_amdgcn_mfma_f32_32x32x16_bf16(pa[kc2], bv2, acc2, 0, 0, 0);
      acc3 = __builtin_amdgcn_mfma_f32_32x32x16_bf16(pa[kc2], bv3, acc3, 0, 0, 0);
    }
    __builtin_amdgcn_s_setprio(0);
    __syncthreads();  // LDS reads done before next tile's DMA
  }

  // ---- epilogue: O[q][d] / l[q] ----
  float linv = 1.f / l_run;
#pragma unroll
  for (int r = 0; r < 16; r++) {
    int qr = (r & 3) + 8 * (r >> 2) + 4 * hh;
    float inv = __shfl(linv, qr);
    int qrow = q0 + 32 * w + qr;
    bf16_t* op = attn + (((size_t)(bS + qrow)) * H_ + h) * D_V_ + ql;
    op[0]  = (bf16_t)(acc0[r] * inv);
    op[32] = (bf16_t)(acc1[r] * inv);
    op[64] = (bf16_t)(acc2[r] * inv);
    op[96] = (bf16_t)(acc3[r] * inv);
  }
}

// ---------------------------------------------------------------------------
extern "C" void kernel_launch(void* const* d_in, const int* in_sizes, int n_in,
                              void* d_out, int out_size, void* d_ws, size_t ws_size,
                              hipStream_t stream) {
  const float* hidden  = (const float*)d_in[0];   // [4096,5120] fp32
  const float* q_a_w   = (const float*)d_in[1];   // [1536,5120] fp32
  const float* q_a_ln  = (const float*)d_in[2];   // [1536] fp32
  const float* q_b_w   = (const float*)d_in[3];   // [6144,1536] fp32
  const float* kv_a_w  = (const float*)d_in[4];   // [576,5120] fp32
  const float* kv_a_ln = (const float*)d_in[5];   // [512] fp32
  const float* kv_b_w  = (const float*)d_in[6];   // [8192,512] fp32
  const float* o_w     = (const float*)d_in[7];   // [5120,4096] fp32
  const int*   pos_ids = (const int*)d_in[8];
  // d_in[9] = attention_mask (causal tril) — hardcoded in flash kernel
  float* out = (float*)d_out;                     // [4096,5120] fp32
  char* ws = (char*)d_ws;
  const int M = B_ * S_;  // 4096

  // workspace layout (bytes); Wslot reused for each converted weight.
  bf16_t* q_ws   = (bf16_t*)(ws + 0);            // 4096x6144 bf16 (50.3MB)
  bf16_t* knF_ws = (bf16_t*)(ws + 50331648);     // KnF frag tiles (33.6MB)
  bf16_t* vF_ws  = (bf16_t*)(ws + 83886080);     // VFg frag tiles (33.6MB)
  bf16_t* kpeF_ws= (bf16_t*)(ws + 117440512);    // KpeF frag tiles (0.5MB)
  bf16_t* Wslot  = (bf16_t*)(ws + 117964800);    // up to 20.97M elems (41.9MB)
  bf16_t* qc_ws  = (bf16_t*)(ws + 159907840);    // 4096x1536 (12.6MB)
  bf16_t* qcn_ws = (bf16_t*)(ws + 172490752);    // 4096x1536 (12.6MB)
  bf16_t* ckv_ws = (bf16_t*)(ws + 185073664);    // 4096x576  (4.7MB)
  bf16_t* ckvn_ws= (bf16_t*)(ws + 189792256);    // 4096x512  (4.2MB) end 193986560
  bf16_t* attn_ws= (bf16_t*)(ws + 159907840);    // 4096x4096 (33.5MB) overlaps qc..ckvn
  // hidden as bf16: overlaps KnF/VFg region (dead until kv_b gemm; hid_bf
  // dies after the kv_a gemm which precedes kv_b).
  bf16_t* hid_bf = (bf16_t*)(ws + 50331648);     // 4096x5120 bf16 (41.9MB)

  // hidden -> bf16 once
  f32_to_bf16_k<<<(int)((4096L * 5120) / 2048), 256, 0, stream>>>(hidden, hid_bf, 4096L * 5120);
  // q_c = hid @ q_a_w^T
  f32_to_bf16_k<<<1536 * 5120 / 2048, 256, 0, stream>>>(q_a_w, Wslot, 1536L * 5120);
  gemm128<0><<<dim3(1536 / 128, M / 128), 256, 0, stream>>>(hid_bf, Wslot, qc_ws, nullptr, M, 1536, 5120);
  rmsnorm_k<<<M, 256, 0, stream>>>(qc_ws, q_a_ln, qcn_ws, 1536, 1536);
  // ckv = hid @ kv_a_w^T  [b,s,576]  (N=576: legacy 64x64 tile; before q_b so
  // hid_bf's lifetime ends before KnF/VFg writes)
  f32_to_bf16_k<<<576 * 5120 / 2048, 256, 0, stream>>>(kv_a_w, Wslot, 576L * 5120);
  gemm_bt64<<<dim3(576 / 64, M / 64), 256, 0, stream>>>(hid_bf, Wslot, ckv_ws, M, 576, 5120);
  rmsnorm_k<<<M, 256, 0, stream>>>(ckv_ws, kv_a_ln, ckvn_ws, 512, 576);
  // q = q_cn @ q_b_w^T  [b,s,h,192]
  f32_to_bf16_k<<<6144 * 1536 / 2048, 256, 0, stream>>>(q_b_w, Wslot, 6144L * 1536);
  gemm128<0><<<dim3(6144 / 128, M / 128), 256, 0, stream>>>(qcn_ws, Wslot, q_ws, nullptr, M, 6144, 1536);
  // kv = ckv_n @ kv_b_w^T -> KnF + VFg fragment-major caches (split epilogue)
  f32_to_bf16_k<<<8192 * 512 / 2048, 256, 0, stream>>>(kv_b_w, Wslot, 8192L * 512);
  gemm128<2><<<dim3(8192 / 128, M / 128), 256, 0, stream>>>(ckvn_ws, Wslot, knF_ws, vF_ws, M, 8192, 512);
  // RoPE: q in-place; k_pe -> KpeF fragment-major cache
  rope_k<<<M * H_, 64, 0, stream>>>(q_ws + 128, q_ws + 128, pos_ids, H_, D_Q_, D_Q_);
  rope_kpe_k<<<M, 64, 0, stream>>>(ckv_ws + 512, kpeF_ws, pos_ids);
  // MFMA flash attention v4 -> attn_ws [b,s,h,128]
  flash_attn4<<<dim3(S_ / 128, B_ * H_), 256, 0, stream>>>(q_ws, knF_ws, kpeF_ws, vF_ws, attn_ws);
  // out = attn @ o_w^T  (fp32 out)
  f32_to_bf16_k<<<5120 * 4096 / 2048, 256, 0, stream>>>(o_w, Wslot, 5120L * 4096);
  gemm128<1><<<dim3(5120 / 128, M / 128), 256, 0, stream>>>(attn_ws, Wslot, out, nullptr, M, 5120, 4096);
}